// Round 1
// baseline (857.871 us; speedup 1.0000x reference)
//
#include <hip/hip_runtime.h>
#include <cmath>

// ---------------------------------------------------------------------------
// Shapes (fixed by the problem): C=256, H=8, D=32, B=8, LQ=256, LKV=1024
//   Nq = 2048 rows, Nkv = 8192 rows. All fp32.
// ---------------------------------------------------------------------------

#define EPS_F 1.1920928955078125e-07f   // np.finfo(np.float32).eps

// ---------------------------------------------------------------------------
// RMSNorm over rows of width 256. One block per row, 256 threads.
// Optionally writes x_n (out_plain) and x_n + pos (out_pos).
// ---------------------------------------------------------------------------
__global__ __launch_bounds__(256) void rmsnorm_dual_kernel(
    const float* __restrict__ X, const float* __restrict__ W,
    const float* __restrict__ pos, float* __restrict__ out_plain,
    float* __restrict__ out_pos)
{
    const int row = blockIdx.x;
    const int tid = threadIdx.x;
    const size_t base = (size_t)row * 256;
    const float v = X[base + tid];
    float sq = v * v;
    #pragma unroll
    for (int m = 1; m < 64; m <<= 1) sq += __shfl_xor(sq, m);
    __shared__ float ws4[4];
    if ((tid & 63) == 0) ws4[tid >> 6] = sq;
    __syncthreads();
    const float total = ws4[0] + ws4[1] + ws4[2] + ws4[3];
    const float ms = total * (1.0f / 256.0f) + EPS_F;
    float inv = rsqrtf(ms);
    inv = inv * (1.5f - 0.5f * ms * inv * inv);   // one Newton step -> full fp32
    const float xn = v * inv * W[tid];
    if (out_plain) out_plain[base + tid] = xn;
    if (out_pos)   out_pos[base + tid] = xn + pos[base + tid];
}

// ---------------------------------------------------------------------------
// fp32 GEMM: C[M][N] = act(A[M][K] @ B[N][K]^T + bias + res)
// 64x64 tile, 256 threads, 4x4 micro-tile per thread, K-chunk 32.
// LDS pad 33 (33 % 32 == 1) -> B column reads conflict-free; A reads broadcast.
// M,N multiples of 64; K multiple of 32 (true for all 9 GEMMs here).
// ACT: 0 = none, 1 = exact GELU.
// ---------------------------------------------------------------------------
template<int ACT, int HAS_BIAS, int HAS_RES>
__global__ __launch_bounds__(256) void gemm_nt_kernel(
    const float* __restrict__ A, const float* __restrict__ B,
    const float* __restrict__ bias, const float* __restrict__ res,
    float* __restrict__ C, int M, int N, int K)
{
    __shared__ float As[64][33];
    __shared__ float Bs[64][33];
    const int bm = blockIdx.x * 64, bn = blockIdx.y * 64;
    const int tid = threadIdx.x;
    const int tr = tid >> 4, tc = tid & 15;
    float acc[4][4] = {{0.f, 0.f, 0.f, 0.f}};

    const int lr = tid >> 2;          // 0..63: staged row
    const int lc = (tid & 3) * 8;     // 0,8,16,24: staged col group
    const float* Ap = A + (size_t)(bm + lr) * K + lc;
    const float* Bp = B + (size_t)(bn + lr) * K + lc;

    for (int k0 = 0; k0 < K; k0 += 32) {
        const float4 a0 = *(const float4*)(Ap + k0);
        const float4 a1 = *(const float4*)(Ap + k0 + 4);
        const float4 b0 = *(const float4*)(Bp + k0);
        const float4 b1 = *(const float4*)(Bp + k0 + 4);
        __syncthreads();   // protect previous iteration's reads
        As[lr][lc+0]=a0.x; As[lr][lc+1]=a0.y; As[lr][lc+2]=a0.z; As[lr][lc+3]=a0.w;
        As[lr][lc+4]=a1.x; As[lr][lc+5]=a1.y; As[lr][lc+6]=a1.z; As[lr][lc+7]=a1.w;
        Bs[lr][lc+0]=b0.x; Bs[lr][lc+1]=b0.y; Bs[lr][lc+2]=b0.z; Bs[lr][lc+3]=b0.w;
        Bs[lr][lc+4]=b1.x; Bs[lr][lc+5]=b1.y; Bs[lr][lc+6]=b1.z; Bs[lr][lc+7]=b1.w;
        __syncthreads();
        #pragma unroll
        for (int kk = 0; kk < 32; ++kk) {
            float a0r = As[tr*4+0][kk], a1r = As[tr*4+1][kk];
            float a2r = As[tr*4+2][kk], a3r = As[tr*4+3][kk];
            float b0r = Bs[tc*4+0][kk], b1r = Bs[tc*4+1][kk];
            float b2r = Bs[tc*4+2][kk], b3r = Bs[tc*4+3][kk];
            acc[0][0] += a0r*b0r; acc[0][1] += a0r*b1r; acc[0][2] += a0r*b2r; acc[0][3] += a0r*b3r;
            acc[1][0] += a1r*b0r; acc[1][1] += a1r*b1r; acc[1][2] += a1r*b2r; acc[1][3] += a1r*b3r;
            acc[2][0] += a2r*b0r; acc[2][1] += a2r*b1r; acc[2][2] += a2r*b2r; acc[2][3] += a2r*b3r;
            acc[3][0] += a3r*b0r; acc[3][1] += a3r*b1r; acc[3][2] += a3r*b2r; acc[3][3] += a3r*b3r;
        }
    }

    #pragma unroll
    for (int i = 0; i < 4; ++i) {
        const int row = bm + tr * 4 + i;
        const int col = bn + tc * 4;
        float o[4];
        #pragma unroll
        for (int j = 0; j < 4; ++j) {
            float v = acc[i][j];
            if (HAS_BIAS) v += bias[col + j];
            if (HAS_RES)  v += res[(size_t)row * N + col + j];
            if (ACT == 1) v = 0.5f * v * (1.0f + erff(v * 0.7071067811865476f));
            o[j] = v;
        }
        *(float4*)(C + (size_t)row * N + col) = make_float4(o[0], o[1], o[2], o[3]);
    }
}

// ---------------------------------------------------------------------------
// Flash-style fp32 attention, head-split layout: row n of Q/K/V matrices holds
// head h at column offset h*32.  Block = 32 q rows x 1 head, 256 threads
// (4 waves x 8 q-rows). Lane l: r = l>>3 (q row within wave), s = l&7 (kv slot:
// lane handles kv indices s, s+8, ... within each 64-wide staged tile).
// Per-lane online softmax over its kv subset; shfl_xor(1,2,4) merge at end.
// self_mask: restrict kv range to the 256-row segment containing q0
// (equivalent to the -10000 block-diagonal bias: exp underflows to exact 0).
// ---------------------------------------------------------------------------
__global__ __launch_bounds__(256) void flash_kernel(
    const float* __restrict__ Q, const float* __restrict__ K,
    const float* __restrict__ V, float* __restrict__ O,
    int q_stride, int kv_stride, int n_kv, int self_mask)
{
    __shared__ float Ks[64][36];   // pad 36: float4-aligned rows, banks spread
    __shared__ float Vs[64][36];
    const int h = blockIdx.y;
    const int q0 = blockIdx.x * 32;
    const int tid = threadIdx.x;
    const int w = tid >> 6, l = tid & 63;
    const int r = l >> 3, s = l & 7;
    const int qrow = q0 + w * 8 + r;
    const float scale = 0.17677669529663687f;   // 32^-0.5

    float qreg[32];
    {
        const float* qp = Q + (size_t)qrow * q_stride + h * 32;
        #pragma unroll
        for (int d4 = 0; d4 < 8; ++d4) {
            float4 t = *(const float4*)(qp + d4 * 4);
            qreg[d4*4+0] = t.x; qreg[d4*4+1] = t.y;
            qreg[d4*4+2] = t.z; qreg[d4*4+3] = t.w;
        }
    }

    const int kv0 = self_mask ? ((q0 >> 8) << 8) : 0;
    float m_run = -1e30f, l_run = 0.f;
    float o[32];
    #pragma unroll
    for (int d = 0; d < 32; ++d) o[d] = 0.f;

    const int lr = tid >> 2, lc = (tid & 3) * 8;   // staging assignment
    for (int t0 = 0; t0 < n_kv; t0 += 64) {
        const float* kp = K + (size_t)(kv0 + t0 + lr) * kv_stride + h * 32 + lc;
        const float* vp = V + (size_t)(kv0 + t0 + lr) * kv_stride + h * 32 + lc;
        const float4 k0v = *(const float4*)kp;
        const float4 k1v = *(const float4*)(kp + 4);
        const float4 v0v = *(const float4*)vp;
        const float4 v1v = *(const float4*)(vp + 4);
        __syncthreads();
        *(float4*)&Ks[lr][lc]     = k0v;
        *(float4*)&Ks[lr][lc + 4] = k1v;
        *(float4*)&Vs[lr][lc]     = v0v;
        *(float4*)&Vs[lr][lc + 4] = v1v;
        __syncthreads();

        #pragma unroll
        for (int i = 0; i < 8; ++i) {
            const int m = s + i * 8;
            float d0 = 0.f, d1 = 0.f, d2 = 0.f, d3 = 0.f;
            #pragma unroll
            for (int d4 = 0; d4 < 8; ++d4) {
                float4 kk = *(const float4*)&Ks[m][d4 * 4];
                d0 += qreg[d4*4+0] * kk.x; d1 += qreg[d4*4+1] * kk.y;
                d2 += qreg[d4*4+2] * kk.z; d3 += qreg[d4*4+3] * kk.w;
            }
            const float sv = ((d0 + d1) + (d2 + d3)) * scale;
            const float newm = fmaxf(m_run, sv);
            const float p = __expf(sv - newm);
            if (newm > m_run) {
                const float c = __expf(m_run - newm);
                l_run *= c;
                #pragma unroll
                for (int d = 0; d < 32; ++d) o[d] *= c;
                m_run = newm;
            }
            l_run += p;
            #pragma unroll
            for (int d4 = 0; d4 < 8; ++d4) {
                float4 vv = *(const float4*)&Vs[m][d4 * 4];
                o[d4*4+0] += p * vv.x; o[d4*4+1] += p * vv.y;
                o[d4*4+2] += p * vv.z; o[d4*4+3] += p * vv.w;
            }
        }
    }

    // merge the 8 kv-slot lanes of each q row (xor masks 1,2,4 stay in group)
    #pragma unroll
    for (int mask = 1; mask <= 4; mask <<= 1) {
        const float m2 = __shfl_xor(m_run, mask);
        const float l2 = __shfl_xor(l_run, mask);
        const float newm = fmaxf(m_run, m2);
        const float c1 = __expf(m_run - newm);
        const float c2 = __expf(m2 - newm);
        l_run = l_run * c1 + l2 * c2;
        #pragma unroll
        for (int d = 0; d < 32; ++d) {
            const float o2 = __shfl_xor(o[d], mask);
            o[d] = o[d] * c1 + o2 * c2;
        }
        m_run = newm;
    }
    const float invl = 1.0f / l_run;

    // all 8 lanes of the group now hold identical o[32]; lane s writes cols s*4..s*4+3.
    // static-index extraction (avoid runtime-indexed register array -> scratch)
    float out0 = 0.f, out1 = 0.f, out2 = 0.f, out3 = 0.f;
    #pragma unroll
    for (int ss = 0; ss < 8; ++ss) {
        if (s == ss) {
            out0 = o[ss*4+0]; out1 = o[ss*4+1];
            out2 = o[ss*4+2]; out3 = o[ss*4+3];
        }
    }
    *(float4*)(O + (size_t)qrow * q_stride + h * 32 + s * 4) =
        make_float4(out0 * invl, out1 * invl, out2 * invl, out3 * invl);
}

// ---------------------------------------------------------------------------
// Launch: 15 kernels. Workspace layout (floats), total ~56 MB:
// ---------------------------------------------------------------------------
extern "C" void kernel_launch(void* const* d_in, const int* in_sizes, int n_in,
                              void* d_out, int out_size, void* d_ws, size_t ws_size,
                              hipStream_t stream)
{
    const float* q         = (const float*)d_in[0];
    const float* kv        = (const float*)d_in[1];
    const float* pos_q     = (const float*)d_in[2];
    const float* pos_k     = (const float*)d_in[3];
    const float* w_norm_kv = (const float*)d_in[4];
    const float* w_norm1   = (const float*)d_in[5];
    const float* w_norm2   = (const float*)d_in[6];
    const float* w_norm3   = (const float*)d_in[7];
    const float* ca_wq     = (const float*)d_in[8];
    const float* ca_wk     = (const float*)d_in[9];
    const float* ca_wv     = (const float*)d_in[10];
    const float* ca_wo     = (const float*)d_in[11];
    const float* ca_bo     = (const float*)d_in[12];
    const float* sa_wq     = (const float*)d_in[13];
    const float* sa_wkv    = (const float*)d_in[14];
    const float* sa_wo     = (const float*)d_in[15];
    const float* sa_bo     = (const float*)d_in[16];
    const float* mlp_w1    = (const float*)d_in[17];
    const float* mlp_b1    = (const float*)d_in[18];
    const float* mlp_w2    = (const float*)d_in[19];
    const float* mlp_b2    = (const float*)d_in[20];
    float* out = (float*)d_out;
    float* ws  = (float*)d_ws;

    float* kvn   = ws;              // 8192*256
    float* kvpk  = ws +  2097152;   // 8192*256
    float* kc    = ws +  4194304;   // 8192*256
    float* vc    = ws +  6291456;   // 8192*256
    float* qpn   = ws +  8388608;   // 2048*256
    float* qc    = ws +  8912896;
    float* feat  = ws +  9437184;
    float* x     = ws +  9961472;
    float* xn2   = ws + 10485760;
    float* xn2p  = ws + 11010048;
    float* qs    = ws + 11534336;
    float* kvs   = ws + 12058624;   // 2048*512
    float* feat2 = ws + 13107200;
    float* x2    = ws + 13631488;
    float* xn3   = ws + 14155776;
    float* hbuf  = ws;              // 2048*1024, reuses kvn/kvpk (dead by then)

    // 1-2: RMSNorms
    rmsnorm_dual_kernel<<<8192, 256, 0, stream>>>(kv, w_norm_kv, pos_k, kvn, kvpk);
    rmsnorm_dual_kernel<<<2048, 256, 0, stream>>>(q, w_norm1, pos_q, nullptr, qpn);
    // 3-5: cross-attn projections
    gemm_nt_kernel<0,0,0><<<dim3( 32, 4), 256, 0, stream>>>(qpn,  ca_wq, nullptr, nullptr, qc, 2048,  256, 256);
    gemm_nt_kernel<0,0,0><<<dim3(128, 4), 256, 0, stream>>>(kvpk, ca_wk, nullptr, nullptr, kc, 8192,  256, 256);
    gemm_nt_kernel<0,0,0><<<dim3(128, 4), 256, 0, stream>>>(kvn,  ca_wv, nullptr, nullptr, vc, 8192,  256, 256);
    // 6: cross attention (dense over all 8192 kv)
    flash_kernel<<<dim3(64, 8), 256, 0, stream>>>(qc, kc, vc, feat, 256, 256, 8192, 0);
    // 7: output proj + residual
    gemm_nt_kernel<0,1,1><<<dim3(32, 4), 256, 0, stream>>>(feat, ca_wo, ca_bo, q, x, 2048, 256, 256);
    // 8: norm2 (both x_n and x_n + pos_q)
    rmsnorm_dual_kernel<<<2048, 256, 0, stream>>>(x, w_norm2, pos_q, xn2, xn2p);
    // 9-10: self-attn projections
    gemm_nt_kernel<0,0,0><<<dim3(32, 4), 256, 0, stream>>>(xn2p, sa_wq,  nullptr, nullptr, qs,  2048, 256, 256);
    gemm_nt_kernel<0,0,0><<<dim3(32, 8), 256, 0, stream>>>(xn2,  sa_wkv, nullptr, nullptr, kvs, 2048, 512, 256);
    // 11: self attention (block-diagonal: 256-row segments)
    flash_kernel<<<dim3(64, 8), 256, 0, stream>>>(qs, kvs, kvs + 256, feat2, 256, 512, 256, 1);
    // 12: output proj + residual
    gemm_nt_kernel<0,1,1><<<dim3(32, 4), 256, 0, stream>>>(feat2, sa_wo, sa_bo, x, x2, 2048, 256, 256);
    // 13: norm3
    rmsnorm_dual_kernel<<<2048, 256, 0, stream>>>(x2, w_norm3, nullptr, xn3, nullptr);
    // 14-15: MLP (exact GELU) + final residual into d_out
    gemm_nt_kernel<1,1,0><<<dim3(32,16), 256, 0, stream>>>(xn3,  mlp_w1, mlp_b1, nullptr, hbuf, 2048, 1024,  256);
    gemm_nt_kernel<0,1,1><<<dim3(32, 4), 256, 0, stream>>>(hbuf, mlp_w2, mlp_b2, x2,     out,  2048,  256, 1024);
}

// Round 2
// 426.740 us; speedup vs baseline: 2.0103x; 2.0103x over previous
//
#include <hip/hip_runtime.h>
#include <cmath>

// ---------------------------------------------------------------------------
// Shapes (fixed): C=256, H=8, D=32, B=8, LQ=256, LKV=1024 -> Nq=2048, Nkv=8192
// ---------------------------------------------------------------------------

#define EPS_F 1.1920928955078125e-07f   // np.finfo(np.float32).eps

typedef __attribute__((ext_vector_type(8))) short short8;
typedef __attribute__((ext_vector_type(4))) short short4v;
typedef __attribute__((ext_vector_type(4))) float f32x4;

// float -> bf16 bits, round-to-nearest-even
__device__ __forceinline__ unsigned short f2bf(float v) {
    union { float f; unsigned int u; } c; c.f = v;
    unsigned int r = c.u + 0x7FFFu + ((c.u >> 16) & 1u);
    return (unsigned short)(r >> 16);
}

// ---------------------------------------------------------------------------
// RMSNorm over rows of width 256. One block per row, 256 threads.
// ---------------------------------------------------------------------------
__global__ __launch_bounds__(256) void rmsnorm_dual_kernel(
    const float* __restrict__ X, const float* __restrict__ W,
    const float* __restrict__ pos, float* __restrict__ out_plain,
    float* __restrict__ out_pos)
{
    const int row = blockIdx.x;
    const int tid = threadIdx.x;
    const size_t base = (size_t)row * 256;
    const float v = X[base + tid];
    float sq = v * v;
    #pragma unroll
    for (int m = 1; m < 64; m <<= 1) sq += __shfl_xor(sq, m);
    __shared__ float ws4[4];
    if ((tid & 63) == 0) ws4[tid >> 6] = sq;
    __syncthreads();
    const float total = ws4[0] + ws4[1] + ws4[2] + ws4[3];
    const float ms = total * (1.0f / 256.0f) + EPS_F;
    float inv = rsqrtf(ms);
    inv = inv * (1.5f - 0.5f * ms * inv * inv);   // Newton -> full fp32
    const float xn = v * inv * W[tid];
    if (out_plain) out_plain[base + tid] = xn;
    if (out_pos)   out_pos[base + tid] = xn + pos[base + tid];
}

// ---------------------------------------------------------------------------
// fp32 GEMM: C[M][N] = act(A[M][K] @ B[N][K]^T + bias + res)
// 64x64 tile, 256 threads, 4x4 micro-tile. OUT_BF16: store bf16 (acc*oscale).
// ---------------------------------------------------------------------------
template<int ACT, int HAS_BIAS, int HAS_RES, int OUT_BF16>
__global__ __launch_bounds__(256) void gemm_nt_kernel(
    const float* __restrict__ A, const float* __restrict__ B,
    const float* __restrict__ bias, const float* __restrict__ res,
    void* __restrict__ Cout, int M, int N, int K, float oscale)
{
    __shared__ float As[64][33];
    __shared__ float Bs[64][33];
    const int bm = blockIdx.x * 64, bn = blockIdx.y * 64;
    const int tid = threadIdx.x;
    const int tr = tid >> 4, tc = tid & 15;
    float acc[4][4] = {{0.f, 0.f, 0.f, 0.f}};

    const int lr = tid >> 2;
    const int lc = (tid & 3) * 8;
    const float* Ap = A + (size_t)(bm + lr) * K + lc;
    const float* Bp = B + (size_t)(bn + lr) * K + lc;

    for (int k0 = 0; k0 < K; k0 += 32) {
        const float4 a0 = *(const float4*)(Ap + k0);
        const float4 a1 = *(const float4*)(Ap + k0 + 4);
        const float4 b0 = *(const float4*)(Bp + k0);
        const float4 b1 = *(const float4*)(Bp + k0 + 4);
        __syncthreads();
        As[lr][lc+0]=a0.x; As[lr][lc+1]=a0.y; As[lr][lc+2]=a0.z; As[lr][lc+3]=a0.w;
        As[lr][lc+4]=a1.x; As[lr][lc+5]=a1.y; As[lr][lc+6]=a1.z; As[lr][lc+7]=a1.w;
        Bs[lr][lc+0]=b0.x; Bs[lr][lc+1]=b0.y; Bs[lr][lc+2]=b0.z; Bs[lr][lc+3]=b0.w;
        Bs[lr][lc+4]=b1.x; Bs[lr][lc+5]=b1.y; Bs[lr][lc+6]=b1.z; Bs[lr][lc+7]=b1.w;
        __syncthreads();
        #pragma unroll
        for (int kk = 0; kk < 32; ++kk) {
            float a0r = As[tr*4+0][kk], a1r = As[tr*4+1][kk];
            float a2r = As[tr*4+2][kk], a3r = As[tr*4+3][kk];
            float b0r = Bs[tc*4+0][kk], b1r = Bs[tc*4+1][kk];
            float b2r = Bs[tc*4+2][kk], b3r = Bs[tc*4+3][kk];
            acc[0][0] += a0r*b0r; acc[0][1] += a0r*b1r; acc[0][2] += a0r*b2r; acc[0][3] += a0r*b3r;
            acc[1][0] += a1r*b0r; acc[1][1] += a1r*b1r; acc[1][2] += a1r*b2r; acc[1][3] += a1r*b3r;
            acc[2][0] += a2r*b0r; acc[2][1] += a2r*b1r; acc[2][2] += a2r*b2r; acc[2][3] += a2r*b3r;
            acc[3][0] += a3r*b0r; acc[3][1] += a3r*b1r; acc[3][2] += a3r*b2r; acc[3][3] += a3r*b3r;
        }
    }

    #pragma unroll
    for (int i = 0; i < 4; ++i) {
        const int row = bm + tr * 4 + i;
        const int col = bn + tc * 4;
        float o[4];
        #pragma unroll
        for (int j = 0; j < 4; ++j) {
            float v = acc[i][j];
            if (HAS_BIAS) v += bias[col + j];
            if (HAS_RES)  v += res[(size_t)row * N + col + j];
            if (ACT == 1) v = 0.5f * v * (1.0f + erff(v * 0.7071067811865476f));
            o[j] = v;
        }
        if (OUT_BF16) {
            unsigned short u0 = f2bf(o[0]*oscale), u1 = f2bf(o[1]*oscale);
            unsigned short u2 = f2bf(o[2]*oscale), u3 = f2bf(o[3]*oscale);
            ushort4 pk; pk.x = u0; pk.y = u1; pk.z = u2; pk.w = u3;
            *(ushort4*)((unsigned short*)Cout + (size_t)row * N + col) = pk;
        } else {
            *(float4*)((float*)Cout + (size_t)row * N + col) = make_float4(o[0], o[1], o[2], o[3]);
        }
    }
}

// ---------------------------------------------------------------------------
// MFMA flash attention (cross-attn), bf16 inputs, fp32 softmax/accum.
// Swapped operands: S^T = K . Q^T  (mfma A=K-frag, B=Q-frag) so lane (q=l&15,
// b=l>>4) holds S[q][kv=16j+4b+i] in acc j, reg i -- which IS the B-operand
// fragment of the PV mfma feat^T = V^T . P^T under the slot enumeration
// kv = 32c + 4b + (e&3) + 16*(e>>2). A/B use the same enumeration, so the
// HW's internal k-permutation cancels (no P redistribution needed).
// Block: 256 thr = 4 waves x 16 q-rows; grid (qtile, head, kv-split).
// Writes unnormalized partials (o, m, l); merge kernel combines splits.
// ---------------------------------------------------------------------------
__global__ __launch_bounds__(256) void flash_mfma_kernel(
    const unsigned short* __restrict__ Qb, const unsigned short* __restrict__ Kb,
    const unsigned short* __restrict__ Vb, float* __restrict__ part_o,
    float* __restrict__ part_ml, int kv_per_split)
{
    __shared__ __align__(16) unsigned short Ks[64 * 32];   // [kv][d] linear
    __shared__ __align__(16) unsigned short Vt[32 * 64];   // [d][kv] swizzled
    const int qtile = blockIdx.x, h = blockIdx.y, split = blockIdx.z;
    const int tid = threadIdx.x;
    const int w = tid >> 6, l = tid & 63;
    const int ql = l & 15, b = l >> 4;
    const int qrow = qtile * 64 + w * 16 + ql;

    // Q fragment (B operand of S^T): Q[qrow][8b..8b+7], pre-scaled by D^-0.5
    short8 qfrag = *(const short8*)(Qb + (size_t)qrow * 256 + h * 32 + b * 8);

    f32x4 oacc0 = {0.f, 0.f, 0.f, 0.f};
    f32x4 oacc1 = {0.f, 0.f, 0.f, 0.f};
    float m_run = -3.0e38f, l_part = 0.f;

    const int kv_base = split * kv_per_split;
    const int ntiles = kv_per_split / 64;
    const int skv = tid >> 2;            // staging kv row 0..63
    const int sd8 = (tid & 3) * 8;       // staging d group

    for (int t = 0; t < ntiles; ++t) {
        const int kvg = kv_base + t * 64;
        short8 kin = *(const short8*)(Kb + (size_t)(kvg + skv) * 256 + h * 32 + sd8);
        short8 vin = *(const short8*)(Vb + (size_t)(kvg + skv) * 256 + h * 32 + sd8);
        __syncthreads();
        *(short8*)(Ks + skv * 32 + sd8) = kin;
        #pragma unroll
        for (int j = 0; j < 8; ++j) {            // transpose V into Vt (swizzled)
            const int d = sd8 + j;
            const int hh = (d + (d >> 3)) & 7;
            Vt[d * 64 + (skv ^ (hh << 3))] = (unsigned short)vin[j];
        }
        __syncthreads();

        // S^T tiles: 4 MFMAs (acc j covers kv 16j..16j+15)
        f32x4 s[4];
        #pragma unroll
        for (int j = 0; j < 4; ++j) {
            short8 kfrag = *(const short8*)(Ks + (j * 16 + ql) * 32 + b * 8);
            f32x4 z = {0.f, 0.f, 0.f, 0.f};
            s[j] = __builtin_amdgcn_mfma_f32_16x16x32_bf16(kfrag, qfrag, z, 0, 0, 0);
        }

        // online softmax (per-lane single q-row; cross-lane only over b-groups)
        float tmax = s[0][0];
        #pragma unroll
        for (int j = 0; j < 4; ++j)
            #pragma unroll
            for (int i = 0; i < 4; ++i) tmax = fmaxf(tmax, s[j][i]);
        tmax = fmaxf(tmax, __shfl_xor(tmax, 16));
        tmax = fmaxf(tmax, __shfl_xor(tmax, 32));
        const float newm = fmaxf(m_run, tmax);
        const float r = __expf(m_run - newm);
        m_run = newm;

        float p[4][4];
        float psum = 0.f;
        #pragma unroll
        for (int j = 0; j < 4; ++j)
            #pragma unroll
            for (int i = 0; i < 4; ++i) {
                p[j][i] = __expf(s[j][i] - newm);
                psum += p[j][i];
            }
        l_part = l_part * r + psum;
        #pragma unroll
        for (int i = 0; i < 4; ++i) { oacc0[i] *= r; oacc1[i] *= r; }

        // pack P -> bf16 B'-frags: chunk c, elem e -> p[2c + (e>>2)][e&3]
        short8 pf0, pf1;
        #pragma unroll
        for (int e = 0; e < 8; ++e) {
            pf0[e] = (short)f2bf(p[(e >> 2)][e & 3]);
            pf1[e] = (short)f2bf(p[2 + (e >> 2)][e & 3]);
        }

        // PV: feat^T = V^T . P^T ; A'-frag elems e -> Vt[d][32c+4b+(e&3)+16(e>>2)]
        #pragma unroll
        for (int tt = 0; tt < 2; ++tt) {
            const int d = 16 * tt + ql;
            const int hh = (d + (d >> 3)) & 7;
            #pragma unroll
            for (int c = 0; c < 2; ++c) {
                short4v lo = *(const short4v*)(Vt + d * 64 + ((32 * c + 4 * b) ^ (hh << 3)));
                short4v hi = *(const short4v*)(Vt + d * 64 + ((32 * c + 16 + 4 * b) ^ (hh << 3)));
                short8 vfrag;
                #pragma unroll
                for (int e = 0; e < 4; ++e) { vfrag[e] = lo[e]; vfrag[e + 4] = hi[e]; }
                if (tt == 0)
                    oacc0 = __builtin_amdgcn_mfma_f32_16x16x32_bf16(vfrag, (c == 0) ? pf0 : pf1, oacc0, 0, 0, 0);
                else
                    oacc1 = __builtin_amdgcn_mfma_f32_16x16x32_bf16(vfrag, (c == 0) ? pf0 : pf1, oacc1, 0, 0, 0);
            }
        }
    }

    float lsum = l_part;
    lsum += __shfl_xor(lsum, 16);
    lsum += __shfl_xor(lsum, 32);

    // write partials: o rows d = 16tt + 4b + i (i contiguous -> float4)
    const size_t obase = ((size_t)split * 2048 + qrow) * 256 + h * 32;
    *(float4*)(part_o + obase + 4 * b)      = make_float4(oacc0[0], oacc0[1], oacc0[2], oacc0[3]);
    *(float4*)(part_o + obase + 16 + 4 * b) = make_float4(oacc1[0], oacc1[1], oacc1[2], oacc1[3]);
    if (b == 0) {
        float* mlp = part_ml + (((size_t)split * 2048 + qrow) * 8 + h) * 2;
        mlp[0] = m_run; mlp[1] = lsum;
    }
}

// ---------------------------------------------------------------------------
// Merge kv-splits: feat = sum_s exp(m_s - M) o_s / sum_s exp(m_s - M) l_s
// ---------------------------------------------------------------------------
__global__ __launch_bounds__(256) void merge_kernel(
    const float* __restrict__ part_o, const float* __restrict__ part_ml,
    float* __restrict__ feat)
{
    const int row = blockIdx.x, c = threadIdx.x;
    const int h = c >> 5;
    float m_s[4], l_s[4];
    float M = -3.0e38f;
    #pragma unroll
    for (int s = 0; s < 4; ++s) {
        const float* mlp = part_ml + (((size_t)s * 2048 + row) * 8 + h) * 2;
        m_s[s] = mlp[0]; l_s[s] = mlp[1];
        M = fmaxf(M, m_s[s]);
    }
    float num = 0.f, den = 0.f;
    #pragma unroll
    for (int s = 0; s < 4; ++s) {
        const float wgt = __expf(m_s[s] - M);
        den += wgt * l_s[s];
        num += wgt * part_o[((size_t)s * 2048 + row) * 256 + c];
    }
    feat[(size_t)row * 256 + c] = num / den;
}

// ---------------------------------------------------------------------------
// fp32 flash attention (kept for block-diagonal self-attn: tiny workload).
// ---------------------------------------------------------------------------
__global__ __launch_bounds__(256) void flash_kernel(
    const float* __restrict__ Q, const float* __restrict__ K,
    const float* __restrict__ V, float* __restrict__ O,
    int q_stride, int kv_stride, int n_kv, int self_mask)
{
    __shared__ float Ksh[64][36];
    __shared__ float Vsh[64][36];
    const int h = blockIdx.y;
    const int q0 = blockIdx.x * 32;
    const int tid = threadIdx.x;
    const int w = tid >> 6, l = tid & 63;
    const int r = l >> 3, s = l & 7;
    const int qrow = q0 + w * 8 + r;
    const float scale = 0.17677669529663687f;

    float qreg[32];
    {
        const float* qp = Q + (size_t)qrow * q_stride + h * 32;
        #pragma unroll
        for (int d4 = 0; d4 < 8; ++d4) {
            float4 t = *(const float4*)(qp + d4 * 4);
            qreg[d4*4+0] = t.x; qreg[d4*4+1] = t.y;
            qreg[d4*4+2] = t.z; qreg[d4*4+3] = t.w;
        }
    }

    const int kv0 = self_mask ? ((q0 >> 8) << 8) : 0;
    float m_run = -1e30f, l_run = 0.f;
    float o[32];
    #pragma unroll
    for (int d = 0; d < 32; ++d) o[d] = 0.f;

    const int lr = tid >> 2, lc = (tid & 3) * 8;
    for (int t0 = 0; t0 < n_kv; t0 += 64) {
        const float* kp = K + (size_t)(kv0 + t0 + lr) * kv_stride + h * 32 + lc;
        const float* vp = V + (size_t)(kv0 + t0 + lr) * kv_stride + h * 32 + lc;
        const float4 k0v = *(const float4*)kp;
        const float4 k1v = *(const float4*)(kp + 4);
        const float4 v0v = *(const float4*)vp;
        const float4 v1v = *(const float4*)(vp + 4);
        __syncthreads();
        *(float4*)&Ksh[lr][lc]     = k0v;
        *(float4*)&Ksh[lr][lc + 4] = k1v;
        *(float4*)&Vsh[lr][lc]     = v0v;
        *(float4*)&Vsh[lr][lc + 4] = v1v;
        __syncthreads();

        #pragma unroll
        for (int i = 0; i < 8; ++i) {
            const int m = s + i * 8;
            float d0 = 0.f, d1 = 0.f, d2 = 0.f, d3 = 0.f;
            #pragma unroll
            for (int d4 = 0; d4 < 8; ++d4) {
                float4 kk = *(const float4*)&Ksh[m][d4 * 4];
                d0 += qreg[d4*4+0] * kk.x; d1 += qreg[d4*4+1] * kk.y;
                d2 += qreg[d4*4+2] * kk.z; d3 += qreg[d4*4+3] * kk.w;
            }
            const float sv = ((d0 + d1) + (d2 + d3)) * scale;
            const float newm = fmaxf(m_run, sv);
            const float p = __expf(sv - newm);
            if (newm > m_run) {
                const float cc = __expf(m_run - newm);
                l_run *= cc;
                #pragma unroll
                for (int d = 0; d < 32; ++d) o[d] *= cc;
                m_run = newm;
            }
            l_run += p;
            #pragma unroll
            for (int d4 = 0; d4 < 8; ++d4) {
                float4 vv = *(const float4*)&Vsh[m][d4 * 4];
                o[d4*4+0] += p * vv.x; o[d4*4+1] += p * vv.y;
                o[d4*4+2] += p * vv.z; o[d4*4+3] += p * vv.w;
            }
        }
    }

    #pragma unroll
    for (int mask = 1; mask <= 4; mask <<= 1) {
        const float m2 = __shfl_xor(m_run, mask);
        const float l2 = __shfl_xor(l_run, mask);
        const float newm = fmaxf(m_run, m2);
        const float c1 = __expf(m_run - newm);
        const float c2 = __expf(m2 - newm);
        l_run = l_run * c1 + l2 * c2;
        #pragma unroll
        for (int d = 0; d < 32; ++d) {
            const float o2 = __shfl_xor(o[d], mask);
            o[d] = o[d] * c1 + o2 * c2;
        }
        m_run = newm;
    }
    const float invl = 1.0f / l_run;

    float out0 = 0.f, out1 = 0.f, out2 = 0.f, out3 = 0.f;
    #pragma unroll
    for (int ss = 0; ss < 8; ++ss) {
        if (s == ss) {
            out0 = o[ss*4+0]; out1 = o[ss*4+1];
            out2 = o[ss*4+2]; out3 = o[ss*4+3];
        }
    }
    *(float4*)(O + (size_t)qrow * q_stride + h * 32 + s * 4) =
        make_float4(out0 * invl, out1 * invl, out2 * invl, out3 * invl);
}

// ---------------------------------------------------------------------------
// Launch. Workspace (floats), ~51 MB; region [0,4M) is time-shared:
//   kvn/kvpk (norms->projections) -> part_o/part_ml (attn) -> hbuf (MLP)
// ---------------------------------------------------------------------------
extern "C" void kernel_launch(void* const* d_in, const int* in_sizes, int n_in,
                              void* d_out, int out_size, void* d_ws, size_t ws_size,
                              hipStream_t stream)
{
    const float* q         = (const float*)d_in[0];
    const float* kv        = (const float*)d_in[1];
    const float* pos_q     = (const float*)d_in[2];
    const float* pos_k     = (const float*)d_in[3];
    const float* w_norm_kv = (const float*)d_in[4];
    const float* w_norm1   = (const float*)d_in[5];
    const float* w_norm2   = (const float*)d_in[6];
    const float* w_norm3   = (const float*)d_in[7];
    const float* ca_wq     = (const float*)d_in[8];
    const float* ca_wk     = (const float*)d_in[9];
    const float* ca_wv     = (const float*)d_in[10];
    const float* ca_wo     = (const float*)d_in[11];
    const float* ca_bo     = (const float*)d_in[12];
    const float* sa_wq     = (const float*)d_in[13];
    const float* sa_wkv    = (const float*)d_in[14];
    const float* sa_wo     = (const float*)d_in[15];
    const float* sa_bo     = (const float*)d_in[16];
    const float* mlp_w1    = (const float*)d_in[17];
    const float* mlp_b1    = (const float*)d_in[18];
    const float* mlp_w2    = (const float*)d_in[19];
    const float* mlp_b2    = (const float*)d_in[20];
    float* out = (float*)d_out;
    float* ws  = (float*)d_ws;

    float* kvn     = ws;                       // [0, 2M)
    float* kvpk    = ws + 2097152;             // [2M, 4M)
    float* part_o  = ws;                       // [0, 2M)   reuse after kc/vc
    float* part_ml = ws + 2097152;             // [2M, 2.13M)
    float* hbuf    = ws;                       // [0, 2M)   reuse after merge
    unsigned short* kc_bf = (unsigned short*)(ws + 4194304);   // 2M ushorts
    unsigned short* vc_bf = (unsigned short*)(ws + 5242880);
    unsigned short* qc_bf = (unsigned short*)(ws + 6291456);   // 0.5M ushorts
    float* qpn   = ws + 6553600;
    float* feat  = ws + 7077888;
    float* x     = ws + 7602176;
    float* xn2   = ws + 8126464;
    float* xn2p  = ws + 8650752;
    float* qs    = ws + 9175040;
    float* kvs   = ws + 9699328;               // 2048*512
    float* feat2 = ws + 10747904;
    float* x2    = ws + 11272192;
    float* xn3   = ws + 11796480;

    const float qscale = 0.17677669529663687f;  // D^-0.5 folded into q cast

    // 1-2: RMSNorms
    rmsnorm_dual_kernel<<<8192, 256, 0, stream>>>(kv, w_norm_kv, pos_k, kvn, kvpk);
    rmsnorm_dual_kernel<<<2048, 256, 0, stream>>>(q, w_norm1, pos_q, nullptr, qpn);
    // 3-5: cross-attn projections -> bf16
    gemm_nt_kernel<0,0,0,1><<<dim3( 32, 4), 256, 0, stream>>>(qpn,  ca_wq, nullptr, nullptr, qc_bf, 2048, 256, 256, qscale);
    gemm_nt_kernel<0,0,0,1><<<dim3(128, 4), 256, 0, stream>>>(kvpk, ca_wk, nullptr, nullptr, kc_bf, 8192, 256, 256, 1.0f);
    gemm_nt_kernel<0,0,0,1><<<dim3(128, 4), 256, 0, stream>>>(kvn,  ca_wv, nullptr, nullptr, vc_bf, 8192, 256, 256, 1.0f);
    // 6-7: MFMA cross attention (kv split 4-way) + merge
    flash_mfma_kernel<<<dim3(32, 8, 4), 256, 0, stream>>>(qc_bf, kc_bf, vc_bf, part_o, part_ml, 2048);
    merge_kernel<<<2048, 256, 0, stream>>>(part_o, part_ml, feat);
    // 8: output proj + residual
    gemm_nt_kernel<0,1,1,0><<<dim3(32, 4), 256, 0, stream>>>(feat, ca_wo, ca_bo, q, x, 2048, 256, 256, 1.0f);
    // 9: norm2
    rmsnorm_dual_kernel<<<2048, 256, 0, stream>>>(x, w_norm2, pos_q, xn2, xn2p);
    // 10-11: self-attn projections (fp32)
    gemm_nt_kernel<0,0,0,0><<<dim3(32, 4), 256, 0, stream>>>(xn2p, sa_wq,  nullptr, nullptr, qs,  2048, 256, 256, 1.0f);
    gemm_nt_kernel<0,0,0,0><<<dim3(32, 8), 256, 0, stream>>>(xn2,  sa_wkv, nullptr, nullptr, kvs, 2048, 512, 256, 1.0f);
    // 12: self attention (block-diagonal, fp32)
    flash_kernel<<<dim3(64, 8), 256, 0, stream>>>(qs, kvs, kvs + 256, feat2, 256, 512, 256, 1);
    // 13: output proj + residual
    gemm_nt_kernel<0,1,1,0><<<dim3(32, 4), 256, 0, stream>>>(feat2, sa_wo, sa_bo, x, x2, 2048, 256, 256, 1.0f);
    // 14: norm3
    rmsnorm_dual_kernel<<<2048, 256, 0, stream>>>(x2, w_norm3, nullptr, xn3, nullptr);
    // 15-16: MLP (exact GELU) + final residual into d_out
    gemm_nt_kernel<1,1,0,0><<<dim3(32,16), 256, 0, stream>>>(xn3,  mlp_w1, mlp_b1, nullptr, hbuf, 2048, 1024, 256, 1.0f);
    gemm_nt_kernel<0,1,1,0><<<dim3(32, 4), 256, 0, stream>>>(hbuf, mlp_w2, mlp_b2, x2,     out,  2048, 256, 1024, 1.0f);
}

// Round 6
// 234.255 us; speedup vs baseline: 3.6621x; 1.8217x over previous
//
#include <hip/hip_runtime.h>
#include <cmath>

// ---------------------------------------------------------------------------
// Shapes (fixed): C=256, H=8, D=32, B=8, LQ=256, LKV=1024 -> Nq=2048, Nkv=8192
// Full bf16-MFMA pipeline; fp32 residual stream and fp32 accumulation.
// ---------------------------------------------------------------------------

#define EPS_F 1.1920928955078125e-07f   // np.finfo(np.float32).eps

typedef __attribute__((ext_vector_type(8))) short short8;
typedef __attribute__((ext_vector_type(4))) short short4v;
typedef __attribute__((ext_vector_type(4))) float f32x4;

// float -> bf16 bits, round-to-nearest-even
__device__ __forceinline__ unsigned short f2bf(float v) {
    union { float f; unsigned int u; } c; c.f = v;
    unsigned int r = c.u + 0x7FFFu + ((c.u >> 16) & 1u);
    return (unsigned short)(r >> 16);
}
__device__ __forceinline__ float bf2f(unsigned short u) {
    union { unsigned int u; float f; } c; c.u = ((unsigned int)u) << 16;
    return c.f;
}

// ---------------------------------------------------------------------------
// Cast 16 x 65536 fp32 weight elements to one contiguous bf16 pool.
// grid 512 blocks x 256 thr, 8 elems/thread.
// ---------------------------------------------------------------------------
struct WPtrs { const float* p[16]; };

__global__ __launch_bounds__(256) void cast_weights_kernel(
    WPtrs wp, unsigned short* __restrict__ outw)
{
    const int unit = blockIdx.x >> 5;
    const int off = ((blockIdx.x & 31) * 256 + threadIdx.x) * 8;
    const float* src = wp.p[unit];
    const float4 v0 = *(const float4*)(src + off);
    const float4 v1 = *(const float4*)(src + off + 4);
    short8 o;
    o[0] = (short)f2bf(v0.x); o[1] = (short)f2bf(v0.y);
    o[2] = (short)f2bf(v0.z); o[3] = (short)f2bf(v0.w);
    o[4] = (short)f2bf(v1.x); o[5] = (short)f2bf(v1.y);
    o[6] = (short)f2bf(v1.z); o[7] = (short)f2bf(v1.w);
    *(short8*)(outw + unit * 65536 + off) = o;
}

// ---------------------------------------------------------------------------
// RMSNorm over rows of width 256 -> bf16 outputs (x_n and optionally x_n+pos).
// ---------------------------------------------------------------------------
__global__ __launch_bounds__(256) void rmsnorm_dual_kernel(
    const float* __restrict__ X, const float* __restrict__ W,
    const float* __restrict__ pos, unsigned short* __restrict__ out_plain,
    unsigned short* __restrict__ out_pos)
{
    const int row = blockIdx.x;
    const int tid = threadIdx.x;
    const size_t base = (size_t)row * 256;
    const float v = X[base + tid];
    float sq = v * v;
    #pragma unroll
    for (int m = 1; m < 64; m <<= 1) sq += __shfl_xor(sq, m);
    __shared__ float ws4[4];
    if ((tid & 63) == 0) ws4[tid >> 6] = sq;
    __syncthreads();
    const float total = ws4[0] + ws4[1] + ws4[2] + ws4[3];
    const float ms = total * (1.0f / 256.0f) + EPS_F;
    float inv = rsqrtf(ms);
    inv = inv * (1.5f - 0.5f * ms * inv * inv);   // Newton -> full fp32
    const float xn = v * inv * W[tid];
    if (out_plain) out_plain[base + tid] = f2bf(xn);
    if (out_pos)   out_pos[base + tid] = f2bf(xn + pos[base + tid]);
}

// ---------------------------------------------------------------------------
// bf16 NT MFMA GEMM: C[M][N] = act(A[M][K] @ B[N][K]^T + bias + res)
// A,B bf16; accum fp32; C fp32 or bf16 (scaled by oscale).
// 64x64 tile, 4 waves, each wave one 32x32 quadrant (2x2 16x16 frags), BK=64.
// LDS tiles XOR-swizzled (byte ^= (row&7)<<4): frag ds_read_b128 <=2-way.
// Next K-chunk prefetched into regs before the compute barrier.
// ---------------------------------------------------------------------------
template<int ACT, int HAS_BIAS, int HAS_RES, int OUT_BF16>
__global__ __launch_bounds__(256) void gemm_bf16_kernel(
    const unsigned short* __restrict__ A, const unsigned short* __restrict__ Bw,
    const float* __restrict__ bias, const float* __restrict__ res,
    void* __restrict__ Cout, int M, int N, int K, float oscale)
{
    __shared__ __align__(16) char As[64 * 128];
    __shared__ __align__(16) char Bs[64 * 128];
    const int bm = blockIdx.x * 64, bn = blockIdx.y * 64;
    const int tid = threadIdx.x;
    const int w = tid >> 6, l = tid & 63;
    const int ql = l & 15, b = l >> 4;
    const int wr = w >> 1, wc = w & 1;

    f32x4 acc[2][2];
    #pragma unroll
    for (int m = 0; m < 2; ++m)
        #pragma unroll
        for (int n = 0; n < 2; ++n) acc[m][n] = (f32x4){0.f, 0.f, 0.f, 0.f};

    const int srow = tid >> 3;             // 0..31
    const int scolb = (tid & 7) * 16;      // byte col slot
    const unsigned short* Ap0 = A + (size_t)(bm + srow) * K + (tid & 7) * 8;
    const unsigned short* Ap1 = A + (size_t)(bm + srow + 32) * K + (tid & 7) * 8;
    const unsigned short* Bp0 = Bw + (size_t)(bn + srow) * K + (tid & 7) * 8;
    const unsigned short* Bp1 = Bw + (size_t)(bn + srow + 32) * K + (tid & 7) * 8;
    const int sw0 = (srow * 128 + scolb) ^ ((srow & 7) << 4);
    const int sw1 = ((srow + 32) * 128 + scolb) ^ ((srow & 7) << 4);

    short8 ra0 = *(const short8*)(Ap0);
    short8 ra1 = *(const short8*)(Ap1);
    short8 rb0 = *(const short8*)(Bp0);
    short8 rb1 = *(const short8*)(Bp1);

    for (int k0 = 0; k0 < K; k0 += 64) {
        __syncthreads();   // protect LDS readers of previous chunk
        *(short8*)(As + sw0) = ra0;
        *(short8*)(As + sw1) = ra1;
        *(short8*)(Bs + sw0) = rb0;
        *(short8*)(Bs + sw1) = rb1;
        if (k0 + 64 < K) {                 // prefetch next chunk (hidden by MFMA)
            ra0 = *(const short8*)(Ap0 + k0 + 64);
            ra1 = *(const short8*)(Ap1 + k0 + 64);
            rb0 = *(const short8*)(Bp0 + k0 + 64);
            rb1 = *(const short8*)(Bp1 + k0 + 64);
        }
        __syncthreads();
        #pragma unroll
        for (int ks = 0; ks < 2; ++ks) {
            short8 af[2], bfr[2];
            #pragma unroll
            for (int m = 0; m < 2; ++m) {
                const int row = wr * 32 + m * 16 + ql;
                af[m] = *(const short8*)(As + ((row * 128 + ks * 64 + b * 16) ^ ((row & 7) << 4)));
            }
            #pragma unroll
            for (int n = 0; n < 2; ++n) {
                const int row = wc * 32 + n * 16 + ql;
                bfr[n] = *(const short8*)(Bs + ((row * 128 + ks * 64 + b * 16) ^ ((row & 7) << 4)));
            }
            #pragma unroll
            for (int m = 0; m < 2; ++m)
                #pragma unroll
                for (int n = 0; n < 2; ++n)
                    acc[m][n] = __builtin_amdgcn_mfma_f32_16x16x32_bf16(af[m], bfr[n], acc[m][n], 0, 0, 0);
        }
    }

    // epilogue: lane (ql,b) frag (m,n) reg r -> C[wr*32+m*16+4b+r][wc*32+n*16+ql]
    #pragma unroll
    for (int m = 0; m < 2; ++m) {
        #pragma unroll
        for (int n = 0; n < 2; ++n) {
            const int col = bn + wc * 32 + n * 16 + ql;
            #pragma unroll
            for (int r = 0; r < 4; ++r) {
                const int row = bm + wr * 32 + m * 16 + 4 * b + r;
                float v = acc[m][n][r];
                if (HAS_BIAS) v += bias[col];
                if (HAS_RES)  v += res[(size_t)row * N + col];
                if (ACT == 1) v = 0.5f * v * (1.0f + erff(v * 0.7071067811865476f));
                if (OUT_BF16)
                    ((unsigned short*)Cout)[(size_t)row * N + col] = f2bf(v * oscale);
                else
                    ((float*)Cout)[(size_t)row * N + col] = v;
            }
        }
    }
}

// ---------------------------------------------------------------------------
// MFMA flash attention, bf16 in, fp32 softmax/accum. Swapped operands:
// S^T = K . Q^T so lane (q=l&15, b=l>>4) holds a full q-row slice; the S^T
// accumulator IS the PV B-operand fragment under the consistent slot
// enumeration (A/B frags agree, HW k-permutation cancels).
// SELF=0: kv split over blockIdx.z, writes unnormalized partials (o, m, l).
// SELF=1: kv range = the q-tile's 256-row segment; writes normalized bf16.
// ---------------------------------------------------------------------------
template<int SELF>
__global__ __launch_bounds__(256) void flash_mfma_kernel(
    const unsigned short* __restrict__ Qb, const unsigned short* __restrict__ Kb,
    const unsigned short* __restrict__ Vb, float* __restrict__ part_o,
    float* __restrict__ part_ml, unsigned short* __restrict__ out_bf,
    int kv_stride, int kv_per_split)
{
    __shared__ __align__(16) unsigned short Ks[64 * 32];   // [kv][d] linear
    __shared__ __align__(16) unsigned short Vt[32 * 64];   // [d][kv] swizzled
    const int qtile = blockIdx.x, h = blockIdx.y, split = blockIdx.z;
    const int tid = threadIdx.x;
    const int w = tid >> 6, l = tid & 63;
    const int ql = l & 15, b = l >> 4;
    const int qrow = qtile * 64 + w * 16 + ql;

    short8 qfrag = *(const short8*)(Qb + (size_t)qrow * 256 + h * 32 + b * 8);

    f32x4 oacc0 = {0.f, 0.f, 0.f, 0.f};
    f32x4 oacc1 = {0.f, 0.f, 0.f, 0.f};
    float m_run = -3.0e38f, l_part = 0.f;

    const int kv_base = SELF ? ((qtile >> 2) << 8) : split * kv_per_split;
    const int ntiles = kv_per_split / 64;
    const int skv = tid >> 2;
    const int sd8 = (tid & 3) * 8;

    for (int t = 0; t < ntiles; ++t) {
        const int kvg = kv_base + t * 64;
        short8 kin = *(const short8*)(Kb + (size_t)(kvg + skv) * kv_stride + h * 32 + sd8);
        short8 vin = *(const short8*)(Vb + (size_t)(kvg + skv) * kv_stride + h * 32 + sd8);
        __syncthreads();
        *(short8*)(Ks + skv * 32 + sd8) = kin;
        #pragma unroll
        for (int j = 0; j < 8; ++j) {            // transpose V into Vt (swizzled)
            const int d = sd8 + j;
            const int hh = (d + (d >> 3)) & 7;
            Vt[d * 64 + (skv ^ (hh << 3))] = (unsigned short)vin[j];
        }
        __syncthreads();

        f32x4 s[4];
        #pragma unroll
        for (int j = 0; j < 4; ++j) {
            short8 kfrag = *(const short8*)(Ks + (j * 16 + ql) * 32 + b * 8);
            f32x4 z = {0.f, 0.f, 0.f, 0.f};
            s[j] = __builtin_amdgcn_mfma_f32_16x16x32_bf16(kfrag, qfrag, z, 0, 0, 0);
        }

        float tmax = s[0][0];
        #pragma unroll
        for (int j = 0; j < 4; ++j)
            #pragma unroll
            for (int i = 0; i < 4; ++i) tmax = fmaxf(tmax, s[j][i]);
        tmax = fmaxf(tmax, __shfl_xor(tmax, 16));
        tmax = fmaxf(tmax, __shfl_xor(tmax, 32));
        const float newm = fmaxf(m_run, tmax);
        const float r = __expf(m_run - newm);
        m_run = newm;

        float p[4][4];
        float psum = 0.f;
        #pragma unroll
        for (int j = 0; j < 4; ++j)
            #pragma unroll
            for (int i = 0; i < 4; ++i) {
                p[j][i] = __expf(s[j][i] - newm);
                psum += p[j][i];
            }
        l_part = l_part * r + psum;
        #pragma unroll
        for (int i = 0; i < 4; ++i) { oacc0[i] *= r; oacc1[i] *= r; }

        short8 pf0, pf1;
        #pragma unroll
        for (int e = 0; e < 8; ++e) {
            pf0[e] = (short)f2bf(p[(e >> 2)][e & 3]);
            pf1[e] = (short)f2bf(p[2 + (e >> 2)][e & 3]);
        }

        #pragma unroll
        for (int tt = 0; tt < 2; ++tt) {
            const int d = 16 * tt + ql;
            const int hh = (d + (d >> 3)) & 7;
            #pragma unroll
            for (int c = 0; c < 2; ++c) {
                short4v lo = *(const short4v*)(Vt + d * 64 + ((32 * c + 4 * b) ^ (hh << 3)));
                short4v hi = *(const short4v*)(Vt + d * 64 + ((32 * c + 16 + 4 * b) ^ (hh << 3)));
                short8 vfrag;
                #pragma unroll
                for (int e = 0; e < 4; ++e) { vfrag[e] = lo[e]; vfrag[e + 4] = hi[e]; }
                if (tt == 0)
                    oacc0 = __builtin_amdgcn_mfma_f32_16x16x32_bf16(vfrag, (c == 0) ? pf0 : pf1, oacc0, 0, 0, 0);
                else
                    oacc1 = __builtin_amdgcn_mfma_f32_16x16x32_bf16(vfrag, (c == 0) ? pf0 : pf1, oacc1, 0, 0, 0);
            }
        }
    }

    float lsum = l_part;
    lsum += __shfl_xor(lsum, 16);
    lsum += __shfl_xor(lsum, 32);

    if (SELF) {
        const float invl = 1.0f / lsum;
        unsigned short* op = out_bf + (size_t)qrow * 256 + h * 32;
        #pragma unroll
        for (int i = 0; i < 4; ++i) {
            op[4 * b + i]      = f2bf(oacc0[i] * invl);
            op[16 + 4 * b + i] = f2bf(oacc1[i] * invl);
        }
    } else {
        const size_t obase = ((size_t)split * 2048 + qrow) * 256 + h * 32;
        *(float4*)(part_o + obase + 4 * b)      = make_float4(oacc0[0], oacc0[1], oacc0[2], oacc0[3]);
        *(float4*)(part_o + obase + 16 + 4 * b) = make_float4(oacc1[0], oacc1[1], oacc1[2], oacc1[3]);
        if (b == 0) {
            float* mlp = part_ml + (((size_t)split * 2048 + qrow) * 8 + h) * 2;
            mlp[0] = m_run; mlp[1] = lsum;
        }
    }
}

// ---------------------------------------------------------------------------
// Merge kv-splits -> bf16 feat.
// ---------------------------------------------------------------------------
__global__ __launch_bounds__(256) void merge_kernel(
    const float* __restrict__ part_o, const float* __restrict__ part_ml,
    unsigned short* __restrict__ feat)
{
    const int row = blockIdx.x, c = threadIdx.x;
    const int h = c >> 5;
    float m_s[4], l_s[4];
    float M = -3.0e38f;
    #pragma unroll
    for (int s = 0; s < 4; ++s) {
        const float* mlp = part_ml + (((size_t)s * 2048 + row) * 8 + h) * 2;
        m_s[s] = mlp[0]; l_s[s] = mlp[1];
        M = fmaxf(M, m_s[s]);
    }
    float num = 0.f, den = 0.f;
    #pragma unroll
    for (int s = 0; s < 4; ++s) {
        const float wgt = __expf(m_s[s] - M);
        den += wgt * l_s[s];
        num += wgt * part_o[((size_t)s * 2048 + row) * 256 + c];
    }
    feat[(size_t)row * 256 + c] = f2bf(num / den);
}

// ---------------------------------------------------------------------------
// Launch: 17 kernels. Workspace (float units), ~47 MB, no aliasing.
// ---------------------------------------------------------------------------
extern "C" void kernel_launch(void* const* d_in, const int* in_sizes, int n_in,
                              void* d_out, int out_size, void* d_ws, size_t ws_size,
                              hipStream_t stream)
{
    const float* q         = (const float*)d_in[0];
    const float* kv        = (const float*)d_in[1];
    const float* pos_q     = (const float*)d_in[2];
    const float* pos_k     = (const float*)d_in[3];
    const float* w_norm_kv = (const float*)d_in[4];
    const float* w_norm1   = (const float*)d_in[5];
    const float* w_norm2   = (const float*)d_in[6];
    const float* w_norm3   = (const float*)d_in[7];
    const float* ca_wq     = (const float*)d_in[8];
    const float* ca_wk     = (const float*)d_in[9];
    const float* ca_wv     = (const float*)d_in[10];
    const float* ca_wo     = (const float*)d_in[11];
    const float* ca_bo     = (const float*)d_in[12];
    const float* sa_wq     = (const float*)d_in[13];
    const float* sa_wkv    = (const float*)d_in[14];
    const float* sa_wo     = (const float*)d_in[15];
    const float* sa_bo     = (const float*)d_in[16];
    const float* mlp_w1    = (const float*)d_in[17];
    const float* mlp_b1    = (const float*)d_in[18];
    const float* mlp_w2    = (const float*)d_in[19];
    const float* mlp_b2    = (const float*)d_in[20];
    float* out = (float*)d_out;
    float* ws  = (float*)d_ws;

    // bf16 buffers are addressed as ushort; sizes tracked in float units (=2 ush)
    unsigned short* wbf      = (unsigned short*)(ws);            // 16*65536 ush
    unsigned short* kvn_bf   = (unsigned short*)(ws +  524288);  // 8192x256
    unsigned short* kvpk_bf  = (unsigned short*)(ws + 1572864);
    unsigned short* kc_bf    = (unsigned short*)(ws + 2621440);
    unsigned short* vc_bf    = (unsigned short*)(ws + 3670016);
    unsigned short* qpn_bf   = (unsigned short*)(ws + 4718592);  // 2048x256
    unsigned short* qc_bf    = (unsigned short*)(ws + 4980736);
    float*          part_o   = ws + 5242880;                     // 4x2048x256 f32
    float*          part_ml  = ws + 7340032;
    unsigned short* feat_bf  = (unsigned short*)(ws + 7471104);
    float*          x        = ws + 7733248;                     // 2048x256 f32
    unsigned short* xn2_bf   = (unsigned short*)(ws + 8257536);
    unsigned short* xn2p_bf  = (unsigned short*)(ws + 8519680);
    unsigned short* qs_bf    = (unsigned short*)(ws + 8781824);
    unsigned short* kvs_bf   = (unsigned short*)(ws + 9043968);  // 2048x512
    unsigned short* feat2_bf = (unsigned short*)(ws + 9568256);
    float*          x2       = ws + 9830400;
    unsigned short* xn3_bf   = (unsigned short*)(ws + 10354688);
    unsigned short* hbuf_bf  = (unsigned short*)(ws + 10616832); // 2048x1024

    unsigned short* wq_bf     = wbf;
    unsigned short* wk_bf     = wbf + 65536;
    unsigned short* wv_bf     = wbf + 131072;
    unsigned short* wo_bf     = wbf + 196608;
    unsigned short* sa_wq_bf  = wbf + 262144;
    unsigned short* sa_wkv_bf = wbf + 327680;
    unsigned short* sa_wo_bf  = wbf + 458752;
    unsigned short* mlp_w1_bf = wbf + 524288;
    unsigned short* mlp_w2_bf = wbf + 786432;

    WPtrs wp;
    wp.p[0] = ca_wq;  wp.p[1] = ca_wk;  wp.p[2] = ca_wv;  wp.p[3] = ca_wo;
    wp.p[4] = sa_wq;  wp.p[5] = sa_wkv; wp.p[6] = sa_wkv + 65536;
    wp.p[7] = sa_wo;
    wp.p[8] = mlp_w1;           wp.p[9]  = mlp_w1 + 65536;
    wp.p[10] = mlp_w1 + 131072; wp.p[11] = mlp_w1 + 196608;
    wp.p[12] = mlp_w2;          wp.p[13] = mlp_w2 + 65536;
    wp.p[14] = mlp_w2 + 131072; wp.p[15] = mlp_w2 + 196608;

    const float qscale = 0.17677669529663687f;  // D^-0.5 folded into q cast

    // 0: weights -> bf16
    cast_weights_kernel<<<512, 256, 0, stream>>>(wp, wbf);
    // 1-2: RMSNorms -> bf16
    rmsnorm_dual_kernel<<<8192, 256, 0, stream>>>(kv, w_norm_kv, pos_k, kvn_bf, kvpk_bf);
    rmsnorm_dual_kernel<<<2048, 256, 0, stream>>>(q, w_norm1, pos_q, nullptr, qpn_bf);
    // 3-5: cross-attn projections (bf16 MFMA)
    gemm_bf16_kernel<0,0,0,1><<<dim3( 32, 4), 256, 0, stream>>>(qpn_bf,  wq_bf, nullptr, nullptr, qc_bf, 2048, 256, 256, qscale);
    gemm_bf16_kernel<0,0,0,1><<<dim3(128, 4), 256, 0, stream>>>(kvpk_bf, wk_bf, nullptr, nullptr, kc_bf, 8192, 256, 256, 1.0f);
    gemm_bf16_kernel<0,0,0,1><<<dim3(128, 4), 256, 0, stream>>>(kvn_bf,  wv_bf, nullptr, nullptr, vc_bf, 8192, 256, 256, 1.0f);
    // 6-7: MFMA cross attention (kv split 4-way) + merge
    flash_mfma_kernel<0><<<dim3(32, 8, 4), 256, 0, stream>>>(qc_bf, kc_bf, vc_bf, part_o, part_ml, nullptr, 256, 2048);
    merge_kernel<<<2048, 256, 0, stream>>>(part_o, part_ml, feat_bf);
    // 8: output proj + residual (fp32 out)
    gemm_bf16_kernel<0,1,1,0><<<dim3(32, 4), 256, 0, stream>>>(feat_bf, wo_bf, ca_bo, q, x, 2048, 256, 256, 1.0f);
    // 9: norm2
    rmsnorm_dual_kernel<<<2048, 256, 0, stream>>>(x, w_norm2, pos_q, xn2_bf, xn2p_bf);
    // 10-11: self-attn projections
    gemm_bf16_kernel<0,0,0,1><<<dim3(32, 4), 256, 0, stream>>>(xn2p_bf, sa_wq_bf,  nullptr, nullptr, qs_bf,  2048, 256, 256, qscale);
    gemm_bf16_kernel<0,0,0,1><<<dim3(32, 8), 256, 0, stream>>>(xn2_bf,  sa_wkv_bf, nullptr, nullptr, kvs_bf, 2048, 512, 256, 1.0f);
    // 12: self attention (block-diagonal segments, normalized bf16 out)
    flash_mfma_kernel<1><<<dim3(32, 8, 1), 256, 0, stream>>>(qs_bf, kvs_bf, kvs_bf + 256, nullptr, nullptr, feat2_bf, 512, 256);
    // 13: output proj + residual
    gemm_bf16_kernel<0,1,1,0><<<dim3(32, 4), 256, 0, stream>>>(feat2_bf, sa_wo_bf, sa_bo, x, x2, 2048, 256, 256, 1.0f);
    // 14: norm3
    rmsnorm_dual_kernel<<<2048, 256, 0, stream>>>(x2, w_norm3, nullptr, xn3_bf, nullptr);
    // 15-16: MLP (exact GELU, bf16 hidden) + final residual into d_out
    gemm_bf16_kernel<1,1,0,1><<<dim3(32,16), 256, 0, stream>>>(xn3_bf,  mlp_w1_bf, mlp_b1, nullptr, hbuf_bf, 2048, 1024, 256, 1.0f);
    gemm_bf16_kernel<0,1,1,0><<<dim3(32, 4), 256, 0, stream>>>(hbuf_bf, mlp_w2_bf, mlp_b2, x2, out, 2048, 256, 1024, 1.0f);
}

// Round 10
// 232.238 us; speedup vs baseline: 3.6939x; 1.0087x over previous
//
#include <hip/hip_runtime.h>
#include <hip/hip_bf16.h>
#include <cmath>

// ---------------------------------------------------------------------------
// Shapes (fixed): C=256, H=8, D=32, B=8, LQ=256, LKV=1024 -> Nq=2048, Nkv=8192
// Full bf16-MFMA pipeline; fp32 residual stream and fp32 accumulation.
// K/V for both attentions are stored by the projection GEMMs directly in
// MFMA-fragment order (+bank swizzle), so the flash kernel's LDS staging is a
// straight vector copy and every fragment is one ds_read_b128.
// ---------------------------------------------------------------------------

#define EPS_F 1.1920928955078125e-07f   // np.finfo(np.float32).eps

typedef __attribute__((ext_vector_type(8))) short short8;
typedef __attribute__((ext_vector_type(4))) float f32x4;

// float -> bf16 bits, round-to-nearest-even (manual; used in epilogues)
__device__ __forceinline__ unsigned short f2bf(float v) {
    union { float f; unsigned int u; } c; c.f = v;
    unsigned int r = c.u + 0x7FFFu + ((c.u >> 16) & 1u);
    return (unsigned short)(r >> 16);
}
// native conversion (compiler may emit v_cvt_pk_bf16_f32) — flash hot path
__device__ __forceinline__ unsigned short f2bf_n(float v) {
    union { __hip_bfloat16 h; unsigned short u; } cv;
    cv.h = __float2bfloat16(v);
    return cv.u;
}

// ---------------------------------------------------------------------------
// Fragment-layout index functions. Tile = 64 kv x 32 d = 2048 ushorts (4KB).
// K: element (kv,d) -> tile (h*Gk + kv/64), idx = (row*32+d) ^ ((row&7)<<3),
//    row = kv&63. Flash A-frag (lane ql,b; sub-tile j) is then 8 contiguous
//    ushorts at ((j*16+ql)*32 + b*8) ^ ((ql&7)<<3).
// V: element (kv,d) stored so that PV A'-frag (lane ql,b; tt,c) with elems
//    e=0..7 -> kv = 32c+4b+(e&3)+16*(e>>2), d = 16tt+ql is 8 contiguous
//    ushorts at tt*1024 + ((ql*64 + c*32 + b*8) ^ ((ql&7)<<3)).
// XOR spreads rows across 16B bank slots: frag reads <=2-way conflict (free).
// ---------------------------------------------------------------------------
__device__ __forceinline__ size_t kfrag_idx(int kv, int col, int Gk) {
    const int h = col >> 5, d = col & 31;
    const int g = kv >> 6, row = kv & 63;
    const int idx = (row * 32 + d) ^ ((row & 7) << 3);
    return ((size_t)(h * Gk + g)) * 2048 + idx;
}
__device__ __forceinline__ size_t vfrag_idx(int kv, int col, int Gk) {
    const int h = col >> 5, d = col & 31;
    const int tt = d >> 4, qd = d & 15;
    const int g = kv >> 6, r6 = kv & 63;
    const int c = r6 >> 5, r5 = r6 & 31;
    const int hi = r5 >> 4, lo4 = r5 & 15;
    const int b = lo4 >> 2, e = (hi << 2) | (lo4 & 3);
    const int idx = tt * 1024 + ((qd * 64 + c * 32 + b * 8 + e) ^ ((qd & 7) << 3));
    return ((size_t)(h * Gk + g)) * 2048 + idx;
}

// ---------------------------------------------------------------------------
// Cast 16 x 65536 fp32 weight elements to one contiguous bf16 pool.
// ---------------------------------------------------------------------------
struct WPtrs { const float* p[16]; };

__global__ __launch_bounds__(256) void cast_weights_kernel(
    WPtrs wp, unsigned short* __restrict__ outw)
{
    const int unit = blockIdx.x >> 5;
    const int off = ((blockIdx.x & 31) * 256 + threadIdx.x) * 8;
    const float* src = wp.p[unit];
    const float4 v0 = *(const float4*)(src + off);
    const float4 v1 = *(const float4*)(src + off + 4);
    short8 o;
    o[0] = (short)f2bf(v0.x); o[1] = (short)f2bf(v0.y);
    o[2] = (short)f2bf(v0.z); o[3] = (short)f2bf(v0.w);
    o[4] = (short)f2bf(v1.x); o[5] = (short)f2bf(v1.y);
    o[6] = (short)f2bf(v1.z); o[7] = (short)f2bf(v1.w);
    *(short8*)(outw + unit * 65536 + off) = o;
}

// ---------------------------------------------------------------------------
// RMSNorm over rows of width 256 -> bf16 outputs.
// ---------------------------------------------------------------------------
__global__ __launch_bounds__(256) void rmsnorm_dual_kernel(
    const float* __restrict__ X, const float* __restrict__ W,
    const float* __restrict__ pos, unsigned short* __restrict__ out_plain,
    unsigned short* __restrict__ out_pos)
{
    const int row = blockIdx.x;
    const int tid = threadIdx.x;
    const size_t base = (size_t)row * 256;
    const float v = X[base + tid];
    float sq = v * v;
    #pragma unroll
    for (int m = 1; m < 64; m <<= 1) sq += __shfl_xor(sq, m);
    __shared__ float ws4[4];
    if ((tid & 63) == 0) ws4[tid >> 6] = sq;
    __syncthreads();
    const float total = ws4[0] + ws4[1] + ws4[2] + ws4[3];
    const float ms = total * (1.0f / 256.0f) + EPS_F;
    float inv = rsqrtf(ms);
    inv = inv * (1.5f - 0.5f * ms * inv * inv);   // Newton -> full fp32
    const float xn = v * inv * W[tid];
    if (out_plain) out_plain[base + tid] = f2bf(xn);
    if (out_pos)   out_pos[base + tid] = f2bf(xn + pos[base + tid]);
}

// ---------------------------------------------------------------------------
// bf16 NT MFMA GEMM: C[M][N] = act(A[M][K] @ B[N][K]^T + bias + res)
// STORE: 0=linear f32, 1=linear bf16*oscale, 2=K-frag bf16*oscale,
//        3=V-frag bf16*oscale, 4=KV split (col<256 -> K-frag Cout,
//        col>=256 -> V-frag Cout2), Gk = kv tiles per head.
// ---------------------------------------------------------------------------
template<int ACT, int HAS_BIAS, int HAS_RES, int STORE>
__global__ __launch_bounds__(256) void gemm_bf16_kernel(
    const unsigned short* __restrict__ A, const unsigned short* __restrict__ Bw,
    const float* __restrict__ bias, const float* __restrict__ res,
    void* __restrict__ Cout, void* __restrict__ Cout2,
    int M, int N, int K, float oscale, int Gk)
{
    __shared__ __align__(16) char As[64 * 128];
    __shared__ __align__(16) char Bs[64 * 128];
    const int bm = blockIdx.x * 64, bn = blockIdx.y * 64;
    const int tid = threadIdx.x;
    const int w = tid >> 6, l = tid & 63;
    const int ql = l & 15, b = l >> 4;
    const int wr = w >> 1, wc = w & 1;

    f32x4 acc[2][2];
    #pragma unroll
    for (int m = 0; m < 2; ++m)
        #pragma unroll
        for (int n = 0; n < 2; ++n) acc[m][n] = (f32x4){0.f, 0.f, 0.f, 0.f};

    const int srow = tid >> 3;
    const int scolb = (tid & 7) * 16;
    const unsigned short* Ap0 = A + (size_t)(bm + srow) * K + (tid & 7) * 8;
    const unsigned short* Ap1 = A + (size_t)(bm + srow + 32) * K + (tid & 7) * 8;
    const unsigned short* Bp0 = Bw + (size_t)(bn + srow) * K + (tid & 7) * 8;
    const unsigned short* Bp1 = Bw + (size_t)(bn + srow + 32) * K + (tid & 7) * 8;
    const int sw0 = (srow * 128 + scolb) ^ ((srow & 7) << 4);
    const int sw1 = ((srow + 32) * 128 + scolb) ^ ((srow & 7) << 4);

    short8 ra0 = *(const short8*)(Ap0);
    short8 ra1 = *(const short8*)(Ap1);
    short8 rb0 = *(const short8*)(Bp0);
    short8 rb1 = *(const short8*)(Bp1);

    for (int k0 = 0; k0 < K; k0 += 64) {
        __syncthreads();
        *(short8*)(As + sw0) = ra0;
        *(short8*)(As + sw1) = ra1;
        *(short8*)(Bs + sw0) = rb0;
        *(short8*)(Bs + sw1) = rb1;
        if (k0 + 64 < K) {
            ra0 = *(const short8*)(Ap0 + k0 + 64);
            ra1 = *(const short8*)(Ap1 + k0 + 64);
            rb0 = *(const short8*)(Bp0 + k0 + 64);
            rb1 = *(const short8*)(Bp1 + k0 + 64);
        }
        __syncthreads();
        #pragma unroll
        for (int ks = 0; ks < 2; ++ks) {
            short8 af[2], bfr[2];
            #pragma unroll
            for (int m = 0; m < 2; ++m) {
                const int row = wr * 32 + m * 16 + ql;
                af[m] = *(const short8*)(As + ((row * 128 + ks * 64 + b * 16) ^ ((row & 7) << 4)));
            }
            #pragma unroll
            for (int n = 0; n < 2; ++n) {
                const int row = wc * 32 + n * 16 + ql;
                bfr[n] = *(const short8*)(Bs + ((row * 128 + ks * 64 + b * 16) ^ ((row & 7) << 4)));
            }
            #pragma unroll
            for (int m = 0; m < 2; ++m)
                #pragma unroll
                for (int n = 0; n < 2; ++n)
                    acc[m][n] = __builtin_amdgcn_mfma_f32_16x16x32_bf16(af[m], bfr[n], acc[m][n], 0, 0, 0);
        }
    }

    #pragma unroll
    for (int m = 0; m < 2; ++m) {
        #pragma unroll
        for (int n = 0; n < 2; ++n) {
            const int col = bn + wc * 32 + n * 16 + ql;
            #pragma unroll
            for (int r = 0; r < 4; ++r) {
                const int row = bm + wr * 32 + m * 16 + 4 * b + r;
                float v = acc[m][n][r];
                if (HAS_BIAS) v += bias[col];
                if (HAS_RES)  v += res[(size_t)row * N + col];
                if (ACT == 1) v = 0.5f * v * (1.0f + erff(v * 0.7071067811865476f));
                if (STORE == 0)
                    ((float*)Cout)[(size_t)row * N + col] = v;
                else if (STORE == 1)
                    ((unsigned short*)Cout)[(size_t)row * N + col] = f2bf(v * oscale);
                else if (STORE == 2)
                    ((unsigned short*)Cout)[kfrag_idx(row, col, Gk)] = f2bf(v * oscale);
                else if (STORE == 3)
                    ((unsigned short*)Cout)[vfrag_idx(row, col, Gk)] = f2bf(v * oscale);
                else {
                    if (col < 256)
                        ((unsigned short*)Cout)[kfrag_idx(row, col, Gk)] = f2bf(v);
                    else
                        ((unsigned short*)Cout2)[vfrag_idx(row, col - 256, Gk)] = f2bf(v);
                }
            }
        }
    }
}

// ---------------------------------------------------------------------------
// MFMA flash attention, fragment-layout K/V, fp32 softmax (log2 domain).
// Block = 4 waves x 16 q-rows; per tile: linear-copy 4KB K + 4KB V to LDS,
// 4 QK^T MFMAs, wave-local softmax (defer-max), 4 PV MFMAs. No transposes.
// SELF=0: kv split over blockIdx.z -> unnormalized partials (o, m, l).
// SELF=1: kv tiles = q-tile's 256-row segment -> normalized bf16 out.
// ---------------------------------------------------------------------------
template<int SELF>
__global__ __launch_bounds__(256) void flash_mfma_kernel(
    const unsigned short* __restrict__ Qb, const unsigned short* __restrict__ Kp,
    const unsigned short* __restrict__ Vp, float* __restrict__ part_o,
    float* __restrict__ part_ml, unsigned short* __restrict__ out_bf,
    int Gk, int ntiles)
{
    __shared__ __align__(16) unsigned short Kt[2048];
    __shared__ __align__(16) unsigned short Vt[2048];
    const int qtile = blockIdx.x, h = blockIdx.y, split = blockIdx.z;
    const int tid = threadIdx.x;
    const int w = tid >> 6, l = tid & 63;
    const int ql = l & 15, b = l >> 4;
    const int qrow = qtile * 64 + w * 16 + ql;

    short8 qfrag = *(const short8*)(Qb + (size_t)qrow * 256 + h * 32 + b * 8);

    const int g0 = SELF ? ((qtile >> 2) << 2) : split * ntiles;
    const unsigned short* Ksrc = Kp + ((size_t)(h * Gk + g0)) * 2048 + tid * 8;
    const unsigned short* Vsrc = Vp + ((size_t)(h * Gk + g0)) * 2048 + tid * 8;

    const int xsw = (ql & 7) << 3;
    const int kb  = (ql * 32 + b * 8) ^ xsw;          // + j*512
    const int vb0 = (ql * 64 + b * 8) ^ xsw;          // c=0; + tt*1024
    const int vb1 = (ql * 64 + 32 + b * 8) ^ xsw;     // c=1

    f32x4 oacc0 = {0.f, 0.f, 0.f, 0.f};
    f32x4 oacc1 = {0.f, 0.f, 0.f, 0.f};
    float m_run = -3.0e38f, l_part = 0.f;

    short8 kpre = *(const short8*)Ksrc;
    short8 vpre = *(const short8*)Vsrc;

    for (int t = 0; t < ntiles; ++t) {
        __syncthreads();
        *(short8*)(Kt + tid * 8) = kpre;
        *(short8*)(Vt + tid * 8) = vpre;
        if (t + 1 < ntiles) {
            kpre = *(const short8*)(Ksrc + (size_t)(t + 1) * 2048);
            vpre = *(const short8*)(Vsrc + (size_t)(t + 1) * 2048);
        }
        __syncthreads();

        f32x4 s[4];
        #pragma unroll
        for (int j = 0; j < 4; ++j) {
            short8 kf = *(const short8*)(Kt + kb + j * 512);
            f32x4 z = {0.f, 0.f, 0.f, 0.f};
            s[j] = __builtin_amdgcn_mfma_f32_16x16x32_bf16(kf, qfrag, z, 0, 0, 0);
        }

        float tmax = s[0][0];
        #pragma unroll
        for (int j = 0; j < 4; ++j)
            #pragma unroll
            for (int i = 0; i < 4; ++i) tmax = fmaxf(tmax, s[j][i]);
        tmax = fmaxf(tmax, __shfl_xor(tmax, 16));
        tmax = fmaxf(tmax, __shfl_xor(tmax, 32));

        // defer-max: rescale only when some row's max grew by > 8 (log2)
        if (!__all(tmax <= m_run + 8.f)) {
            const float newm = fmaxf(m_run, tmax);
            const float r = exp2f(m_run - newm);
            l_part *= r;
            #pragma unroll
            for (int i = 0; i < 4; ++i) { oacc0[i] *= r; oacc1[i] *= r; }
            m_run = newm;
        }

        float p[4][4];
        float psum = 0.f;
        #pragma unroll
        for (int j = 0; j < 4; ++j)
            #pragma unroll
            for (int i = 0; i < 4; ++i) {
                p[j][i] = exp2f(s[j][i] - m_run);
                psum += p[j][i];
            }
        l_part += psum;

        short8 pf0, pf1;
        #pragma unroll
        for (int e = 0; e < 8; ++e) {
            pf0[e] = (short)f2bf_n(p[(e >> 2)][e & 3]);
            pf1[e] = (short)f2bf_n(p[2 + (e >> 2)][e & 3]);
        }

        short8 v00 = *(const short8*)(Vt + vb0);
        short8 v01 = *(const short8*)(Vt + vb1);
        short8 v10 = *(const short8*)(Vt + 1024 + vb0);
        short8 v11 = *(const short8*)(Vt + 1024 + vb1);
        oacc0 = __builtin_amdgcn_mfma_f32_16x16x32_bf16(v00, pf0, oacc0, 0, 0, 0);
        oacc0 = __builtin_amdgcn_mfma_f32_16x16x32_bf16(v01, pf1, oacc0, 0, 0, 0);
        oacc1 = __builtin_amdgcn_mfma_f32_16x16x32_bf16(v10, pf0, oacc1, 0, 0, 0);
        oacc1 = __builtin_amdgcn_mfma_f32_16x16x32_bf16(v11, pf1, oacc1, 0, 0, 0);
    }

    float lsum = l_part;
    lsum += __shfl_xor(lsum, 16);
    lsum += __shfl_xor(lsum, 32);

    if (SELF) {
        const float invl = 1.0f / lsum;
        unsigned short* op = out_bf + (size_t)qrow * 256 + h * 32;
        #pragma unroll
        for (int i = 0; i < 4; ++i) {
            op[4 * b + i]      = f2bf(oacc0[i] * invl);
            op[16 + 4 * b + i] = f2bf(oacc1[i] * invl);
        }
    } else {
        const size_t obase = ((size_t)split * 2048 + qrow) * 256 + h * 32;
        *(float4*)(part_o + obase + 4 * b)      = make_float4(oacc0[0], oacc0[1], oacc0[2], oacc0[3]);
        *(float4*)(part_o + obase + 16 + 4 * b) = make_float4(oacc1[0], oacc1[1], oacc1[2], oacc1[3]);
        if (b == 0) {
            float* mlp = part_ml + (((size_t)split * 2048 + qrow) * 8 + h) * 2;
            mlp[0] = m_run; mlp[1] = lsum;
        }
    }
}

// ---------------------------------------------------------------------------
// Merge 8 kv-splits -> bf16 feat (log2-domain m).
// ---------------------------------------------------------------------------
__global__ __launch_bounds__(256) void merge_kernel(
    const float* __restrict__ part_o, const float* __restrict__ part_ml,
    unsigned short* __restrict__ feat)
{
    const int row = blockIdx.x, c = threadIdx.x;
    const int h = c >> 5;
    float m_s[8], l_s[8];
    float M = -3.0e38f;
    #pragma unroll
    for (int s = 0; s < 8; ++s) {
        const float* mlp = part_ml + (((size_t)s * 2048 + row) * 8 + h) * 2;
        m_s[s] = mlp[0]; l_s[s] = mlp[1];
        M = fmaxf(M, m_s[s]);
    }
    float num = 0.f, den = 0.f;
    #pragma unroll
    for (int s = 0; s < 8; ++s) {
        const float wgt = exp2f(m_s[s] - M);
        den += wgt * l_s[s];
        num += wgt * part_o[((size_t)s * 2048 + row) * 256 + c];
    }
    feat[(size_t)row * 256 + c] = f2bf(num / den);
}

// ---------------------------------------------------------------------------
// Launch. Workspace (float units), ~55.6 MB, no aliasing.
// ---------------------------------------------------------------------------
extern "C" void kernel_launch(void* const* d_in, const int* in_sizes, int n_in,
                              void* d_out, int out_size, void* d_ws, size_t ws_size,
                              hipStream_t stream)
{
    const float* q         = (const float*)d_in[0];
    const float* kv        = (const float*)d_in[1];
    const float* pos_q     = (const float*)d_in[2];
    const float* pos_k     = (const float*)d_in[3];
    const float* w_norm_kv = (const float*)d_in[4];
    const float* w_norm1   = (const float*)d_in[5];
    const float* w_norm2   = (const float*)d_in[6];
    const float* w_norm3   = (const float*)d_in[7];
    const float* ca_wq     = (const float*)d_in[8];
    const float* ca_wk     = (const float*)d_in[9];
    const float* ca_wv     = (const float*)d_in[10];
    const float* ca_wo     = (const float*)d_in[11];
    const float* ca_bo     = (const float*)d_in[12];
    const float* sa_wq     = (const float*)d_in[13];
    const float* sa_wkv    = (const float*)d_in[14];
    const float* sa_wo     = (const float*)d_in[15];
    const float* sa_bo     = (const float*)d_in[16];
    const float* mlp_w1    = (const float*)d_in[17];
    const float* mlp_b1    = (const float*)d_in[18];
    const float* mlp_w2    = (const float*)d_in[19];
    const float* mlp_b2    = (const float*)d_in[20];
    float* out = (float*)d_out;
    float* ws  = (float*)d_ws;

    unsigned short* wbf      = (unsigned short*)(ws);             // [0, 524288)
    unsigned short* kvn_bf   = (unsigned short*)(ws +   524288);  // 8192x256
    unsigned short* kvpk_bf  = (unsigned short*)(ws +  1572864);
    unsigned short* kc_p     = (unsigned short*)(ws +  2621440);  // K-frag, Gk=128
    unsigned short* vc_p     = (unsigned short*)(ws +  3670016);  // V-frag, Gk=128
    unsigned short* qpn_bf   = (unsigned short*)(ws +  4718592);  // 2048x256
    unsigned short* qc_bf    = (unsigned short*)(ws +  4980736);
    float*          part_o   = ws +  5242880;                     // 8x2048x256 f32
    float*          part_ml  = ws +  9437184;                     // 8x2048x8x2
    unsigned short* feat_bf  = (unsigned short*)(ws +  9699328);
    float*          x        = ws +  9961472;                     // 2048x256 f32
    unsigned short* xn2_bf   = (unsigned short*)(ws + 10485760);
    unsigned short* xn2p_bf  = (unsigned short*)(ws + 10747904);
    unsigned short* qs_bf    = (unsigned short*)(ws + 11010048);
    unsigned short* kp_s     = (unsigned short*)(ws + 11272192);  // K-frag, Gk=32
    unsigned short* vp_s     = (unsigned short*)(ws + 11534336);  // V-frag, Gk=32
    unsigned short* feat2_bf = (unsigned short*)(ws + 11796480);
    float*          x2       = ws + 12058624;
    unsigned short* xn3_bf   = (unsigned short*)(ws + 12582912);
    unsigned short* hbuf_bf  = (unsigned short*)(ws + 12845056);  // 2048x1024

    unsigned short* wq_bf     = wbf;
    unsigned short* wk_bf     = wbf + 65536;
    unsigned short* wv_bf     = wbf + 131072;
    unsigned short* wo_bf     = wbf + 196608;
    unsigned short* sa_wq_bf  = wbf + 262144;
    unsigned short* sa_wkv_bf = wbf + 327680;
    unsigned short* sa_wo_bf  = wbf + 458752;
    unsigned short* mlp_w1_bf = wbf + 524288;
    unsigned short* mlp_w2_bf = wbf + 786432;

    WPtrs wp;
    wp.p[0] = ca_wq;  wp.p[1] = ca_wk;  wp.p[2] = ca_wv;  wp.p[3] = ca_wo;
    wp.p[4] = sa_wq;  wp.p[5] = sa_wkv; wp.p[6] = sa_wkv + 65536;
    wp.p[7] = sa_wo;
    wp.p[8] = mlp_w1;           wp.p[9]  = mlp_w1 + 65536;
    wp.p[10] = mlp_w1 + 131072; wp.p[11] = mlp_w1 + 196608;
    wp.p[12] = mlp_w2;          wp.p[13] = mlp_w2 + 65536;
    wp.p[14] = mlp_w2 + 131072; wp.p[15] = mlp_w2 + 196608;

    // D^-0.5 * log2(e): softmax computed in exp2 domain
    const float qscale = 0.17677669529663687f * 1.4426950408889634f;

    // 0: weights -> bf16
    cast_weights_kernel<<<512, 256, 0, stream>>>(wp, wbf);
    // 1-2: RMSNorms -> bf16
    rmsnorm_dual_kernel<<<8192, 256, 0, stream>>>(kv, w_norm_kv, pos_k, kvn_bf, kvpk_bf);
    rmsnorm_dual_kernel<<<2048, 256, 0, stream>>>(q, w_norm1, pos_q, nullptr, qpn_bf);
    // 3-5: cross-attn projections (qc linear scaled; kc/vc fragment layout)
    gemm_bf16_kernel<0,0,0,1><<<dim3( 32, 4), 256, 0, stream>>>(qpn_bf,  wq_bf, nullptr, nullptr, qc_bf, nullptr, 2048, 256, 256, qscale, 0);
    gemm_bf16_kernel<0,0,0,2><<<dim3(128, 4), 256, 0, stream>>>(kvpk_bf, wk_bf, nullptr, nullptr, kc_p,  nullptr, 8192, 256, 256, 1.0f, 128);
    gemm_bf16_kernel<0,0,0,3><<<dim3(128, 4), 256, 0, stream>>>(kvn_bf,  wv_bf, nullptr, nullptr, vc_p,  nullptr, 8192, 256, 256, 1.0f, 128);
    // 6-7: MFMA cross attention (kv split 8-way) + merge
    flash_mfma_kernel<0><<<dim3(32, 8, 8), 256, 0, stream>>>(qc_bf, kc_p, vc_p, part_o, part_ml, nullptr, 128, 16);
    merge_kernel<<<2048, 256, 0, stream>>>(part_o, part_ml, feat_bf);
    // 8: output proj + residual (fp32 out)
    gemm_bf16_kernel<0,1,1,0><<<dim3(32, 4), 256, 0, stream>>>(feat_bf, wo_bf, ca_bo, q, x, nullptr, 2048, 256, 256, 1.0f, 0);
    // 9: norm2
    rmsnorm_dual_kernel<<<2048, 256, 0, stream>>>(x, w_norm2, pos_q, xn2_bf, xn2p_bf);
    // 10-11: self-attn projections (qs linear scaled; kv fragment layouts)
    gemm_bf16_kernel<0,0,0,1><<<dim3(32, 4), 256, 0, stream>>>(xn2p_bf, sa_wq_bf,  nullptr, nullptr, qs_bf, nullptr, 2048, 256, 256, qscale, 0);
    gemm_bf16_kernel<0,0,0,4><<<dim3(32, 8), 256, 0, stream>>>(xn2_bf,  sa_wkv_bf, nullptr, nullptr, kp_s,  vp_s,   2048, 512, 256, 1.0f, 32);
    // 12: self attention (block-diagonal segments, normalized bf16 out)
    flash_mfma_kernel<1><<<dim3(32, 8, 1), 256, 0, stream>>>(qs_bf, kp_s, vp_s, nullptr, nullptr, feat2_bf, 32, 4);
    // 13: output proj + residual
    gemm_bf16_kernel<0,1,1,0><<<dim3(32, 4), 256, 0, stream>>>(feat2_bf, sa_wo_bf, sa_bo, x, x2, nullptr, 2048, 256, 256, 1.0f, 0);
    // 14: norm3
    rmsnorm_dual_kernel<<<2048, 256, 0, stream>>>(x2, w_norm3, nullptr, xn3_bf, nullptr);
    // 15-16: MLP (exact GELU, bf16 hidden) + final residual into d_out
    gemm_bf16_kernel<1,1,0,1><<<dim3(32,16), 256, 0, stream>>>(xn3_bf,  mlp_w1_bf, mlp_b1, nullptr, hbuf_bf, nullptr, 2048, 1024, 256, 1.0f, 0);
    gemm_bf16_kernel<0,1,1,0><<<dim3(32, 4), 256, 0, stream>>>(hbuf_bf, mlp_w2_bf, mlp_b2, x2, out, nullptr, 2048, 256, 1024, 1.0f, 0);
}